// Round 8
// baseline (22.989 us; speedup 1.0000x reference)
//
#include <hip/hip_runtime.h>
#include <cstdint>
#include <cstddef>
#include <algorithm>

// ---------------- problem constants ----------------
#define NROW 16      // only bn rows 0..15 feed the outputs (n=16)
#define CTOT 384
#define HW   1024    // 32*32
#define KSEL 20
#define PSEL 96
#define NREM 76      // P - K
#define NUNSEL 1004  // HW - K

#define CPB   4                  // channels per block = 1 per wave (kernel A)
#define SPLIT (CTOT / CPB)       // 96

typedef unsigned long long u64;

struct Perm76 { int p[NREM]; };

// ---------------- conv job: 4x4 tile of one channel, rows in registers, halos via shfl ----------------
__device__ __forceinline__ void conv_job(const float4* f6, const float* w9,
                                         int b, int c, float acc[4][4])
{
  #pragma unroll
  for (int m = 0; m < 6; ++m) {
    float4 f = f6[m];
    const bool dead = (b == 0 && m == 0) || (b == 7 && m == 5);   // out-of-plane row
    if (dead) { f.x = 0.f; f.y = 0.f; f.z = 0.f; f.w = 0.f; }
    float L = __shfl_up(f.w, 1);     // col 4c-1 from lane-1 (row-mask inherited)
    float R = __shfl_down(f.x, 1);   // col 4c+4 from lane+1
    if (c == 0) L = 0.f;
    if (c == 7) R = 0.f;
    const float c6[6] = { L, f.x, f.y, f.z, f.w, R };
    #pragma unroll
    for (int j = 0; j < 4; ++j) {
      const int d = m - j;           // kernel row
      if (d >= 0 && d < 3) {
        #pragma unroll
        for (int k = 0; k < 4; ++k)
          acc[j][k] += c6[k]     * w9[3 * d]
                     + c6[k + 1] * w9[3 * d + 1]
                     + c6[k + 2] * w9[3 * d + 2];
      }
    }
  }
}

// ---------------- kernel A: shuffle-conv, 1 channel/wave -> partial planes ----------------
// grid = NROW*SPLIT (1536) blocks = 6 blocks/CU (24 waves/CU). Block (r,s): channels
// [s*4,(s+1)*4), wave w owns channel s*4+w. Cross-wave sum via 16 KB LDS, float4 store.
__global__ __launch_bounds__(256) void pv_conv(
    const float* __restrict__ feat, const float* __restrict__ dw_w,
    const float* __restrict__ pw_w, float* __restrict__ partial)
{
  __shared__ float red[4][HW];                  // 16 KB
  const int t = threadIdx.x;
  const int w = t >> 6, lane = t & 63;
  const int b = lane >> 3, c = lane & 7;        // 4x4 tile at rows 4b.., cols 4c..
  const int r = blockIdx.x & (NROW - 1);
  const int s = blockIdx.x >> 4;
  const int ch = s * CPB + w;
  const float* base = feat + ((size_t)r * CTOT + ch) * HW;

  // issue all 6 row-loads first (coalesced float4; halo rows dedup in L1/L2)
  float4 f[6];
  #pragma unroll
  for (int m = 0; m < 6; ++m) {
    const int row = 4 * b + m - 1;
    const int rc = row < 0 ? 0 : (row > 31 ? 31 : row);
    f[m] = *reinterpret_cast<const float4*>(base + rc * 32 + 4 * c);
  }

  // fused weights (wave-uniform addresses -> scalar loads)
  float w9[9];
  {
    const float pw = pw_w[ch];
    #pragma unroll
    for (int i = 0; i < 9; ++i) w9[i] = dw_w[ch * 9 + i] * pw;
  }

  float acc[4][4];
  #pragma unroll
  for (int j = 0; j < 4; ++j)
    #pragma unroll
    for (int k = 0; k < 4; ++k) acc[j][k] = 0.f;

  conv_job(f, w9, b, c, acc);

  // cross-wave reduction (disjoint buffers; conflict-free float4 traffic)
  #pragma unroll
  for (int j = 0; j < 4; ++j)
    *reinterpret_cast<float4*>(&red[w][(4 * b + j) * 32 + 4 * c]) =
        make_float4(acc[j][0], acc[j][1], acc[j][2], acc[j][3]);
  __syncthreads();

  float4 sum = make_float4(0.f, 0.f, 0.f, 0.f);
  #pragma unroll
  for (int g = 0; g < 4; ++g) {
    const float4 v = *reinterpret_cast<const float4*>(&red[g][4 * t]);
    sum.x += v.x; sum.y += v.y; sum.z += v.z; sum.w += v.w;
  }
  *reinterpret_cast<float4*>(partial + ((size_t)(r * SPLIT + s)) * HW + 4 * t) = sum;
}

// ---------------- kernel B: reduce 96 planes + slice top-20 + global top-20 + emit ----------------
// grid = NROW blocks, 256 threads. Output: x_out (16*96) then y_out (16*96), int32.
__global__ __launch_bounds__(256) void pv_select(
    const float* __restrict__ partial, int* __restrict__ out, Perm76 perm)
{
  __shared__ u64 keysh[HW];                  // 8 KB
  __shared__ u64 cand[8 * KSEL];             // 160 candidates
  __shared__ int votes[KSEL];
  __shared__ int maskv[HW];
  __shared__ int wsumS[4];
  __shared__ int unsel[NUNSEL];

  const int r = blockIdx.x;
  const int t = threadIdx.x;
  const int lane = t & 63, wv = t >> 6;

  // phase 1: reduce 96 partial planes at px 4t..4t+3 (8-deep MLP, L3-resident)
  const float* bp = partial + (size_t)r * SPLIT * HW + 4 * t;
  float4 A[8];
  #pragma unroll
  for (int i = 0; i < 8; ++i) A[i] = make_float4(0.f, 0.f, 0.f, 0.f);
  for (int s = 0; s < SPLIT; s += 8) {
    #pragma unroll
    for (int i = 0; i < 8; ++i) {
      const float4 v = *reinterpret_cast<const float4*>(bp + (size_t)(s + i) * HW);
      A[i].x += v.x; A[i].y += v.y; A[i].z += v.z; A[i].w += v.w;
    }
  }
  #pragma unroll
  for (int i = 1; i < 8; ++i) {
    A[0].x += A[i].x; A[0].y += A[i].y; A[0].z += A[i].z; A[0].w += A[i].w;
  }

  // phase 2: monotone sortable keys (larger score wins; tie -> smaller index)
  const float sv[4] = { A[0].x, A[0].y, A[0].z, A[0].w };
  u64 key[4];
  #pragma unroll
  for (int q = 0; q < 4; ++q) {
    const int i = 4 * t + q;
    const uint32_t bb = __float_as_uint(sv[q]);
    const uint32_t mm = (bb & 0x80000000u) ? ~bb : (bb | 0x80000000u);
    key[q] = ((u64)mm << 32) | (uint32_t)(1023 - i);
    keysh[i] = key[q];
  }
  maskv[t] = 0; maskv[t + 256] = 0; maskv[t + 512] = 0; maskv[t + 768] = 0;
  __syncthreads();

  // phase 3: slice-local rank (128-px slices; 2 addresses/wave -> free broadcast)
  {
    const u64* sk = &keysh[(t >> 5) * 128];
    int rk0 = 0, rk1 = 0, rk2 = 0, rk3 = 0;
    for (int j = 0; j < 128; ++j) {
      const u64 kj = sk[j];
      rk0 += (kj > key[0]); rk1 += (kj > key[1]);
      rk2 += (kj > key[2]); rk3 += (kj > key[3]);
    }
    const int rk[4] = { rk0, rk1, rk2, rk3 };
    #pragma unroll
    for (int q = 0; q < 4; ++q)
      if (rk[q] < KSEL) cand[(t >> 5) * KSEL + rk[q]] = key[q];
  }
  __syncthreads();

  // phase 4: exact global top-20 (union of slice top-20s contains it)
  if (t < 8 * KSEL) {
    const u64 my = cand[t];
    int rank = 0;
    for (int j = 0; j < 8 * KSEL; ++j) rank += (cand[j] > my);
    if (rank < KSEL) votes[rank] = 1023 - (int)(my & 1023ull);
  }
  __syncthreads();

  // selected coords + mask
  if (t < KSEL) {
    const int idx = votes[t];
    maskv[idx] = 1;
    int xx = idx & 31, yy = idx >> 5;
    if (xx < 1) xx = 1;                      // clip(.,1,31); upper bound can't trigger
    if (yy < 1) yy = 1;
    out[r * PSEL + t]               = xx;
    out[NROW * PSEL + r * PSEL + t] = yy;
  }
  __syncthreads();

  // unselected indices ascending via shfl prefix over !mask
  int cnt = 0;
  #pragma unroll
  for (int j = 0; j < 4; ++j) cnt += (maskv[t * 4 + j] == 0);
  int inc = cnt;
  #pragma unroll
  for (int dd = 1; dd < 64; dd <<= 1) {
    const int o = __shfl_up(inc, dd);
    if (lane >= dd) inc += o;
  }
  if (lane == 63) wsumS[wv] = inc;
  __syncthreads();
  int basep = 0;
  for (int i = 0; i < 4; ++i) if (i < wv) basep += wsumS[i];
  int pos = basep + inc - cnt;               // exclusive prefix
  #pragma unroll
  for (int j = 0; j < 4; ++j) {
    const int i = t * 4 + j;
    if (!maskv[i]) unsel[pos++] = i;
  }
  __syncthreads();

  // random remaining via fixed permutation
  if (t < NREM) {
    const int u = unsel[perm.p[t]];
    int xx = u & 31, yy = u >> 5;
    if (xx < 1) xx = 1;
    if (yy < 1) yy = 1;
    out[r * PSEL + KSEL + t]               = xx;
    out[NROW * PSEL + r * PSEL + KSEL + t] = yy;
  }
}

// ---------------- host: JAX threefry2x32 (partitionable) ----------------
static inline uint32_t rotl32(uint32_t v, uint32_t n) { return (v << n) | (v >> (32 - n)); }

static void tf2x32(uint32_t k0, uint32_t k1, uint32_t x0, uint32_t x1,
                   uint32_t* o0, uint32_t* o1)
{
  const uint32_t ks[3] = { k0, k1, k0 ^ k1 ^ 0x1BD11BDAu };
  static const uint32_t rot[2][4] = { {13, 15, 26, 6}, {17, 29, 16, 24} };
  x0 += ks[0]; x1 += ks[1];
  for (int i = 0; i < 5; ++i) {
    const uint32_t* rr = rot[i & 1];
    for (int j = 0; j < 4; ++j) { x0 += x1; x1 = rotl32(x1, rr[j]); x1 ^= x0; }
    x0 += ks[(i + 1) % 3];
    x1 += ks[(i + 2) % 3] + (uint32_t)(i + 1);
  }
  *o0 = x0; *o1 = x1;
}

// perm = jax.random.permutation(jax.random.key(42), 1004)[:76]  (threefry_partitionable)
static void compute_perm(int* perm_out)
{
  uint32_t bits[NUNSEL];
  uint32_t sk0, sk1;
  { uint32_t o0, o1; tf2x32(0u, 42u, 0u, 1u, &o0, &o1); sk0 = o0; sk1 = o1; }
  for (int i = 0; i < NUNSEL; ++i) {
    uint32_t o0, o1; tf2x32(sk0, sk1, 0u, (uint32_t)i, &o0, &o1);
    bits[i] = o0 ^ o1;
  }
  int idx[NUNSEL];
  for (int i = 0; i < NUNSEL; ++i) idx[i] = i;
  std::stable_sort(idx, idx + NUNSEL, [&](int a, int b) { return bits[a] < bits[b]; });
  for (int j = 0; j < NREM; ++j) perm_out[j] = idx[j];
}

extern "C" void kernel_launch(void* const* d_in, const int* in_sizes, int n_in,
                              void* d_out, int out_size, void* d_ws, size_t ws_size,
                              hipStream_t stream)
{
  (void)in_sizes; (void)n_in; (void)out_size; (void)ws_size;
  const float* feat = (const float*)d_in[0];
  const float* dw_w = (const float*)d_in[1];
  // d_in[2] = dw_b (zeros; constant shift, ordering-irrelevant)
  const float* pw_w = (const float*)d_in[3];
  // d_in[4] = pw_b (constant shift, ordering-irrelevant)
  int*   out     = (int*)d_out;
  float* partial = (float*)d_ws;             // NROW*SPLIT*HW f32 = 6 MB, fully rewritten

  Perm76 perm;
  compute_perm(perm.p);                      // deterministic host compute, kernel-arg baked

  pv_conv<<<NROW * SPLIT, 256, 0, stream>>>(feat, dw_w, pw_w, partial);
  pv_select<<<NROW, 256, 0, stream>>>(partial, out, perm);
}